// Round 3
// baseline (601.322 us; speedup 1.0000x reference)
//
#include <hip/hip_runtime.h>

typedef __attribute__((ext_vector_type(8))) short short8;
typedef __attribute__((ext_vector_type(4))) float float4v;

#define V_ 20000
#define KS 8          // split-K slices (register-accumulated per block)
#define ARS 264       // A LDS row stride in shorts (256 + 8 pad)

__device__ __forceinline__ unsigned short f2bf(float f) {
    union { float f; unsigned int u; } v; v.f = f;
    unsigned int u = v.u;
    u += 0x7fffu + ((u >> 16) & 1u);
    return (unsigned short)(u >> 16);
}

__device__ __forceinline__ float fast_tanh(float x) {
    float xc = fminf(15.f, fmaxf(-15.f, x));
    float e = __expf(2.f * xc);
    return (e - 1.f) / (e + 1.f);   // tanh(0) == 0 exactly (mask depends on it)
}

__device__ __forceinline__ float sigmoidf_(float x) {
    float xc = fminf(30.f, fmaxf(-30.f, x));
    return 1.f / (1.f + __expf(-xc));
}

// ---------------------------------------------------------------- cvt emb -> bf16 transposed [128n][20000k]
__global__ __launch_bounds__(256) void cvt_embT(const float* __restrict__ emb,
                                                unsigned short* __restrict__ embT) {
    __shared__ unsigned short tile[128 * 65];
    int tid = threadIdx.x;
    int k0 = blockIdx.x * 64;
    const float4v* e4 = (const float4v*)emb;
    #pragma unroll
    for (int c = 0; c < 8; ++c) {
        int l4 = c * 256 + tid;      // float4 index in 64k x 128n tile
        int k = l4 >> 5;             // 32 float4 per k-row
        int n4 = l4 & 31;
        float4v f = {0.f, 0.f, 0.f, 0.f};
        if (k0 + k < V_) f = e4[(size_t)(k0 + k) * 32 + n4];
        tile[(n4 * 4 + 0) * 65 + k] = f2bf(f.x);
        tile[(n4 * 4 + 1) * 65 + k] = f2bf(f.y);
        tile[(n4 * 4 + 2) * 65 + k] = f2bf(f.z);
        tile[(n4 * 4 + 3) * 65 + k] = f2bf(f.w);
    }
    __syncthreads();
    #pragma unroll
    for (int c = 0; c < 4; ++c) {
        int l8 = c * 256 + tid;      // n*8 + seg
        int n = l8 >> 3, seg = l8 & 7;
        int kk = k0 + seg * 8;
        if (kk < V_) {
            short8 v;
            #pragma unroll
            for (int i = 0; i < 8; ++i) v[i] = (short)tile[n * 65 + seg * 8 + i];
            *(short8*)(embT + (size_t)n * V_ + kk) = v;
        }
    }
}

// ---------------------------------------------------------------- big GEMM: partial[KS][3232][128]
// M-tile = 16 rows/block so each row is read in 1-KB contiguous chunks (16 lanes x 64 B).
// B fragments come straight from L2/L3-resident embT into registers; only A uses LDS.
// Accumulators live in registers across the block's whole k-slice.
__global__ __launch_bounds__(256) void big_gemm(const float* __restrict__ x,
                                                const float* __restrict__ a,
                                                const unsigned short* __restrict__ embT,
                                                float* __restrict__ partial) {
    __shared__ unsigned short Alds[2][16 * ARS];
    int tid = threadIdx.x;
    int bx = blockIdx.x, by = blockIdx.y;   // bx: M-tile (202), by: k-slice (KS)
    int m0 = bx * 16;
    // distribute 79 sub-chunks (78 x 256k + 1 x 32k) over KS slices
    const int per = 79 / KS, extra = 79 % KS;          // 9, 7
    int sc0 = by * per + (by < extra ? by : extra);
    int nsc = per + (by < extra ? 1 : 0);

    int r = tid >> 4, c = tid & 15;          // staging: row 0..15, 16 threads/row
    int rg = m0 + r;
    const float* __restrict__ srcA = (rg < 3200) ? (x + (size_t)rg * V_)
                                                 : (a + (size_t)(rg - 3200) * V_);
    int lane = tid & 63, w = tid >> 6;
    int ln = lane & 15, quad = lane >> 4;
    const unsigned short* __restrict__ bb0 = embT + (size_t)(w * 32 + ln) * V_ + quad * 8;
    const unsigned short* __restrict__ bb1 = bb0 + (size_t)16 * V_;
    int aoff = ln * ARS + quad * 8;          // A-frag LDS offset (shorts)

    float4v acc0 = {0.f, 0.f, 0.f, 0.f}, acc1 = {0.f, 0.f, 0.f, 0.f};
    float4v p0, p1, p2, p3;

    // ---- prologue: stage sub-chunk sc0 into buf 0
    {
        int k0 = sc0 * 256;
        int nkb = 625 - sc0 * 8; if (nkb > 8) nkb = 8;
        int L = nkb * 32;
        if (c * 16 < L) {
            const float4v* ap = (const float4v*)(srcA + k0 + c * 16);
            p0 = ap[0]; p1 = ap[1]; p2 = ap[2]; p3 = ap[3];
        } else {
            p0 = p1 = p2 = p3 = (float4v){0.f, 0.f, 0.f, 0.f};
        }
        short8 w0, w1;
        w0[0]=(short)f2bf(p0.x); w0[1]=(short)f2bf(p0.y); w0[2]=(short)f2bf(p0.z); w0[3]=(short)f2bf(p0.w);
        w0[4]=(short)f2bf(p1.x); w0[5]=(short)f2bf(p1.y); w0[6]=(short)f2bf(p1.z); w0[7]=(short)f2bf(p1.w);
        w1[0]=(short)f2bf(p2.x); w1[1]=(short)f2bf(p2.y); w1[2]=(short)f2bf(p2.z); w1[3]=(short)f2bf(p2.w);
        w1[4]=(short)f2bf(p3.x); w1[5]=(short)f2bf(p3.y); w1[6]=(short)f2bf(p3.z); w1[7]=(short)f2bf(p3.w);
        *(short8*)&Alds[0][r * ARS + c * 16]     = w0;
        *(short8*)&Alds[0][r * ARS + c * 16 + 8] = w1;
    }
    __syncthreads();

    for (int s = 0; s < nsc; ++s) {
        int buf = s & 1;
        int sc = sc0 + s;
        int k0 = sc * 256;
        int nkb = 625 - sc * 8; if (nkb > 8) nkb = 8;
        bool more = (s + 1 < nsc);
        if (more) {
            int k0n = (sc + 1) * 256;
            int nkbn = 625 - (sc + 1) * 8; if (nkbn > 8) nkbn = 8;
            if (c * 16 < nkbn * 32) {
                const float4v* ap = (const float4v*)(srcA + k0n + c * 16);
                p0 = ap[0]; p1 = ap[1]; p2 = ap[2]; p3 = ap[3];
            } else {
                p0 = p1 = p2 = p3 = (float4v){0.f, 0.f, 0.f, 0.f};
            }
        }
        const unsigned short* bp0 = bb0 + k0;
        const unsigned short* bp1 = bb1 + k0;
        const unsigned short* al = &Alds[buf][aoff];
        if (nkb == 8) {
            #pragma unroll
            for (int kk = 0; kk < 8; ++kk) {
                short8 af = *(const short8*)(al + kk * 32);
                short8 f0 = *(const short8*)(bp0 + kk * 32);
                short8 f1 = *(const short8*)(bp1 + kk * 32);
                acc0 = __builtin_amdgcn_mfma_f32_16x16x32_bf16(af, f0, acc0, 0, 0, 0);
                acc1 = __builtin_amdgcn_mfma_f32_16x16x32_bf16(af, f1, acc1, 0, 0, 0);
            }
        } else {
            for (int kk = 0; kk < nkb; ++kk) {
                short8 af = *(const short8*)(al + kk * 32);
                short8 f0 = *(const short8*)(bp0 + kk * 32);
                short8 f1 = *(const short8*)(bp1 + kk * 32);
                acc0 = __builtin_amdgcn_mfma_f32_16x16x32_bf16(af, f0, acc0, 0, 0, 0);
                acc1 = __builtin_amdgcn_mfma_f32_16x16x32_bf16(af, f1, acc1, 0, 0, 0);
            }
        }
        if (more) {
            int nxt = buf ^ 1;
            short8 w0, w1;
            w0[0]=(short)f2bf(p0.x); w0[1]=(short)f2bf(p0.y); w0[2]=(short)f2bf(p0.z); w0[3]=(short)f2bf(p0.w);
            w0[4]=(short)f2bf(p1.x); w0[5]=(short)f2bf(p1.y); w0[6]=(short)f2bf(p1.z); w0[7]=(short)f2bf(p1.w);
            w1[0]=(short)f2bf(p2.x); w1[1]=(short)f2bf(p2.y); w1[2]=(short)f2bf(p2.z); w1[3]=(short)f2bf(p2.w);
            w1[4]=(short)f2bf(p3.x); w1[5]=(short)f2bf(p3.y); w1[6]=(short)f2bf(p3.z); w1[7]=(short)f2bf(p3.w);
            *(short8*)&Alds[nxt][r * ARS + c * 16]     = w0;
            *(short8*)&Alds[nxt][r * ARS + c * 16 + 8] = w1;
        }
        __syncthreads();
    }

    // epilogue: C/D mapping col=lane&15, row=quad*4+reg
    size_t base = ((size_t)by * 3232 + m0 + quad * 4) * 128 + w * 32 + ln;
    #pragma unroll
    for (int reg = 0; reg < 4; ++reg) {
        partial[base + (size_t)reg * 128]      = acc0[reg];
        partial[base + (size_t)reg * 128 + 16] = acc1[reg];
    }
}

// ---------------------------------------------------------------- reduce K-slices + tanh + mask
__global__ __launch_bounds__(128) void reduce_tanh(const float* __restrict__ partial,
                                                   float* __restrict__ xe,
                                                   float* __restrict__ ae,
                                                   float* __restrict__ maskg) {
    int row = blockIdx.x;   // 0..3231
    int e = threadIdx.x;
    float s = 0.f;
    #pragma unroll
    for (int k = 0; k < KS; ++k)
        s += partial[((size_t)k * 3232 + row) * 128 + e];
    float v = fast_tanh(s);
    if (row < 3200) {
        xe[(size_t)row * 128 + e] = v;
        __shared__ int any;
        if (e == 0) any = 0;
        __syncthreads();
        if (v != 0.f) any = 1;
        __syncthreads();
        if (e == 0) maskg[row] = any ? 1.f : 0.f;
    } else {
        ae[(row - 3200) * 128 + e] = v;
    }
}

// ---------------------------------------------------------------- x_proj = xe @ gru_k + b_i   [3200][384]
__global__ __launch_bounds__(384) void xproj_kernel(const float* __restrict__ xe,
                                                    const float* __restrict__ gru_k,
                                                    const float* __restrict__ b_i,
                                                    float* __restrict__ xproj) {
    __shared__ float xs[16 * 128];
    int tid = threadIdx.x;
    int row0 = blockIdx.x * 16;
    const float4v* src = (const float4v*)(xe + (size_t)row0 * 128);
    float4v* dstl = (float4v*)xs;
    #pragma unroll
    for (int c = 0; c < 2; ++c) {
        int i4 = c * 384 + tid;
        if (i4 < 512) dstl[i4] = src[i4];
    }
    __syncthreads();
    int j = tid;  // 0..383
    float acc[16];
    #pragma unroll
    for (int r = 0; r < 16; ++r) acc[r] = 0.f;
    float bi = b_i[j];
    for (int k4 = 0; k4 < 32; ++k4) {
        float g0 = gru_k[(k4 * 4 + 0) * 384 + j];
        float g1 = gru_k[(k4 * 4 + 1) * 384 + j];
        float g2 = gru_k[(k4 * 4 + 2) * 384 + j];
        float g3 = gru_k[(k4 * 4 + 3) * 384 + j];
        #pragma unroll
        for (int r = 0; r < 16; ++r) {
            float4v xv = *(const float4v*)&xs[r * 128 + k4 * 4];
            acc[r] = fmaf(xv.x, g0, acc[r]);
            acc[r] = fmaf(xv.y, g1, acc[r]);
            acc[r] = fmaf(xv.z, g2, acc[r]);
            acc[r] = fmaf(xv.w, g3, acc[r]);
        }
    }
    #pragma unroll
    for (int r = 0; r < 16; ++r)
        xproj[(size_t)(row0 + r) * 384 + j] = acc[r] + bi;
}

// ---------------------------------------------------------------- GRU scan: 1 block / batch
__global__ __launch_bounds__(384) void gru_kernel(const float* __restrict__ xproj,
                                                  const float* __restrict__ maskg,
                                                  const float* __restrict__ gru_rk,
                                                  const float* __restrict__ b_r,
                                                  float* __restrict__ hout) {
    int b = blockIdx.x;
    int j = threadIdx.x;  // 0..383
    float w[128];
    #pragma unroll
    for (int k = 0; k < 128; ++k) w[k] = gru_rk[k * 384 + j];
    float br = b_r[j];
    __shared__ float4v hs4[32];
    __shared__ float recs[384];
    float* hs = (float*)hs4;
    float hreg = 0.f;
    if (j < 128) hs[j] = 0.f;
    const float* xp_base = xproj + (size_t)b * 100 * 384;
    const float* mk = maskg + b * 100;
    float xz = 0.f, xr = 0.f, xh = 0.f;
    if (j < 128) { xz = xp_base[j]; xr = xp_base[128 + j]; xh = xp_base[256 + j]; }
    __syncthreads();
    for (int t = 0; t < 100; ++t) {
        float nxz = 0.f, nxr = 0.f, nxh = 0.f;
        if (t < 99 && j < 128) {
            const float* nb = xp_base + (t + 1) * 384;
            nxz = nb[j]; nxr = nb[128 + j]; nxh = nb[256 + j];
        }
        float s0 = 0.f, s1 = 0.f, s2 = 0.f, s3 = 0.f;
        #pragma unroll
        for (int k4 = 0; k4 < 32; ++k4) {
            float4v hv = hs4[k4];
            s0 = fmaf(hv.x, w[k4 * 4 + 0], s0);
            s1 = fmaf(hv.y, w[k4 * 4 + 1], s1);
            s2 = fmaf(hv.z, w[k4 * 4 + 2], s2);
            s3 = fmaf(hv.w, w[k4 * 4 + 3], s3);
        }
        recs[j] = br + ((s0 + s1) + (s2 + s3));
        __syncthreads();
        if (j < 128) {
            float z = sigmoidf_(xz + recs[j]);
            float r = sigmoidf_(xr + recs[128 + j]);
            float hh = fast_tanh(xh + r * recs[256 + j]);
            float hn = z * hreg + (1.f - z) * hh;
            hreg = (mk[t] != 0.f) ? hn : hreg;
            hs[j] = hreg;
        }
        __syncthreads();
        xz = nxz; xr = nxr; xh = nxh;
    }
    if (j < 128) hout[b * 128 + j] = hreg;
}

// ---------------------------------------------------------------- head
__global__ __launch_bounds__(64) void head_kernel(const float* __restrict__ hout,
                                                  const float* __restrict__ ae,
                                                  const float* __restrict__ d,
                                                  const float* __restrict__ W1,
                                                  const float* __restrict__ b1,
                                                  const float* __restrict__ W2,
                                                  const float* __restrict__ b2,
                                                  float* __restrict__ out) {
    int b = blockIdx.x;
    int m = threadIdx.x;  // 0..63
    float s = b1[m];
    const float* hb = hout + b * 128;
    const float* ab = ae + b * 128;
    #pragma unroll 4
    for (int k = 0; k < 128; ++k) s = fmaf(hb[k], W1[k * 64 + m], s);
    #pragma unroll 4
    for (int k = 0; k < 128; ++k) s = fmaf(ab[k], W1[(128 + k) * 64 + m], s);
    float c = fast_tanh(s);
    float p = c * W2[m];
    #pragma unroll
    for (int off = 32; off > 0; off >>= 1) p += __shfl_down(p, off);
    if (m == 0) {
        p += d[b * 2 + 0] * W2[64] + d[b * 2 + 1] * W2[65] + b2[0];
        out[b] = sigmoidf_(p);
    }
}

extern "C" void kernel_launch(void* const* d_in, const int* in_sizes, int n_in,
                              void* d_out, int out_size, void* d_ws, size_t ws_size,
                              hipStream_t stream) {
    (void)in_sizes; (void)n_in; (void)out_size; (void)ws_size;
    const float* x      = (const float*)d_in[0];
    const float* a      = (const float*)d_in[1];
    const float* d      = (const float*)d_in[2];
    const float* emb    = (const float*)d_in[3];
    const float* gru_k  = (const float*)d_in[4];
    const float* gru_rk = (const float*)d_in[5];
    const float* gbi    = (const float*)d_in[6];
    const float* gbr    = (const float*)d_in[7];
    const float* W1     = (const float*)d_in[8];
    const float* b1     = (const float*)d_in[9];
    const float* W2     = (const float*)d_in[10];
    const float* b2     = (const float*)d_in[11];
    float* out = (float*)d_out;

    char* ws = (char*)d_ws;
    unsigned short* embT = (unsigned short*)(ws);              //  5,120,000 B
    float* xe      = (float*)(ws + 5120000);                   //  1,638,400 B
    float* ae      = (float*)(ws + 6758400);                   //     16,384 B
    float* maskg   = (float*)(ws + 6774784);                   //     12,800 B
    float* xproj   = (float*)(ws + 6787584);                   //  4,915,200 B
    float* hout    = (float*)(ws + 11702784);                  //     16,384 B
    float* partial = (float*)(ws + 11719168);                  // 13,238,272 B (KS*3232*128*4)

    hipLaunchKernelGGL(cvt_embT,    dim3(313),      dim3(256), 0, stream, emb, embT);
    hipLaunchKernelGGL(big_gemm,    dim3(202, KS),  dim3(256), 0, stream, x, a, embT, partial);
    hipLaunchKernelGGL(reduce_tanh, dim3(3232),     dim3(128), 0, stream, partial, xe, ae, maskg);
    hipLaunchKernelGGL(xproj_kernel,dim3(200),      dim3(384), 0, stream, xe, gru_k, gbi, xproj);
    hipLaunchKernelGGL(gru_kernel,  dim3(32),       dim3(384), 0, stream, xproj, maskg, gru_rk, gbr, hout);
    hipLaunchKernelGGL(head_kernel, dim3(32),       dim3(64),  0, stream, hout, ae, d, W1, b1, W2, b2, out);
}